// Round 4
// baseline (330.398 us; speedup 1.0000x reference)
//
#include <hip/hip_runtime.h>
#include <stdint.h>

// Problem constants (fixed by the reference)
#define NQ 2048
#define NK 4096
#define DFF 2048
#define SPLITS 8

using u16 = unsigned short;
typedef float f32x4 __attribute__((ext_vector_type(4)));
typedef short s16x8 __attribute__((ext_vector_type(8)));

__device__ __forceinline__ float b2f(u16 u) {
  return __uint_as_float(((uint32_t)u) << 16);
}
__device__ __forceinline__ u16 f2b(float f) {
  uint32_t u = __float_as_uint(f);
  uint32_t r = u + 0x7FFFu + ((u >> 16) & 1u);  // RNE
  return (u16)(r >> 16);
}
__device__ __forceinline__ u16 f2h(float f) {           // fp32 -> fp16 bits (RNE)
  _Float16 h = (_Float16)f;
  return __builtin_bit_cast(u16, h);
}
__device__ __forceinline__ float h2f(u16 u) {
  return (float)__builtin_bit_cast(_Float16, u);
}
__device__ __forceinline__ void mfma16(f32x4& d, s16x8 a, s16x8 b) {   // bf16
  asm volatile("v_mfma_f32_16x16x32_bf16 %0, %1, %2, %0" : "+v"(d) : "v"(a), "v"(b));
}
__device__ __forceinline__ void mfma16h(f32x4& d, s16x8 a, s16x8 b) {  // fp16
  asm volatile("v_mfma_f32_16x16x32_f16 %0, %1, %2, %0" : "+v"(d) : "v"(a), "v"(b));
}

// ---------------------------------------------------------------------------
// int64-vs-int32 detector for index inputs (index values < 1024 -> int64 high
// words are all zero; genuine int32 random indices make that probability ~0).
// ---------------------------------------------------------------------------
__global__ void detect_i64_kernel(const int* __restrict__ IP, int* __restrict__ flag) {
  if (threadIdx.x == 0 && blockIdx.x == 0) {
    int f = 1;
    for (int j = 1; j < 128; j += 2) f &= (IP[j] == 0);
    *flag = f;
  }
}

// ---------------------------------------------------------------------------
// fp32 -> bf16 hi(/lo) plane quantizer. lo = bf16(v - hi) gives ~2^-17 rel pair.
// ---------------------------------------------------------------------------
__global__ __launch_bounds__(256) void quant_kernel(
    const float* __restrict__ S, u16* __restrict__ H, u16* __restrict__ L, int n)
{
  int i = blockIdx.x * 256 + threadIdx.x;
  const int stride = gridDim.x * 256;
  for (; i < n; i += stride) {
    float v = S[i];
    u16 h = f2b(v);
    H[i] = h;
    if (L) L[i] = f2b(v - b2f(h));
  }
}

// fp32 -> fp16 single-plane quantizer (for the Wd GEMM: 2^-11 rel)
__global__ __launch_bounds__(256) void quantf16_kernel(
    const float* __restrict__ S, u16* __restrict__ H, int n)
{
  int i = blockIdx.x * 256 + threadIdx.x;
  const int stride = gridDim.x * 256;
  for (; i < n; i += stride) H[i] = f2h(S[i]);
}

// ---------------------------------------------------------------------------
// Equivariant projection: Y[n,o,c] = sum_i W[o,i] * X[n,i,c]  (layout [n][i*3+c])
// fp32 throughout. 2 rows n per block.
// ---------------------------------------------------------------------------
__global__ __launch_bounds__(256) void proj_kernel(
    const float* __restrict__ X, const float* __restrict__ W, float* __restrict__ Y)
{
  __shared__ __align__(16) float xs[2][128][4];
  const int t = threadIdx.x;
  const int n0 = blockIdx.x * 2;
  for (int e = t; e < 768; e += 256) {
    int nl = (e >= 384);
    int r = e - nl * 384;
    xs[nl][r / 3][r % 3] = X[(size_t)(n0 + nl) * 384 + r];
  }
  __syncthreads();
  const int nl = t >> 7, o = t & 127;
  const float4* wrow = (const float4*)(W + o * 128);
  float a0 = 0.f, a1 = 0.f, a2 = 0.f;
#pragma unroll
  for (int j = 0; j < 32; ++j) {
    float4 wv = wrow[j];
    float w[4] = {wv.x, wv.y, wv.z, wv.w};
#pragma unroll
    for (int e = 0; e < 4; ++e) {
      float4 xv = *(const float4*)&xs[nl][j * 4 + e][0];
      a0 = fmaf(w[e], xv.x, a0);
      a1 = fmaf(w[e], xv.y, a1);
      a2 = fmaf(w[e], xv.z, a2);
    }
  }
  const size_t yb = (size_t)(n0 + nl) * 384 + o * 3;
  Y[yb + 0] = a0;
  Y[yb + 1] = a1;
  Y[yb + 2] = a2;
}

// ---------------------------------------------------------------------------
// Gathered multi-head attention, fp32. One block per query n; wave h = head,
// lane l = neighbor (L=64 == wave size).
// ---------------------------------------------------------------------------
__global__ __launch_bounds__(512) void attn_kernel(
    const float* __restrict__ Q, const float* __restrict__ K, const float* __restrict__ V,
    const int* __restrict__ IP, const int* __restrict__ KBC,
    const int* __restrict__ IPB, const int* __restrict__ FLAG, float* __restrict__ O)
{
  const int n = blockIdx.x;
  const int t = threadIdx.x;
  const int h = t >> 6, l = t & 63;
  __shared__ __align__(16) float qs[384];
  __shared__ float attn_s[8][64];
  __shared__ int gi_s[8][64];
  if (t < 96) ((float4*)qs)[t] = ((const float4*)(Q + (size_t)n * 384))[t];
  const int is64 = *FLAG;
  const long long* IP64 = (const long long*)IP;
  const long long* KBC64 = (const long long*)KBC;
  const long long* IPB64 = (const long long*)IPB;
  const int b = is64 ? (int)IPB64[n] : IPB[n];
  int ks0 = 0;
#pragma unroll
  for (int j = 0; j < 4; ++j) {
    int cnt = is64 ? (int)KBC64[j] : KBC[j];
    ks0 += (j < b) ? cnt : 0;  // exclusive cumsum
  }
  const int ip = is64 ? (int)IP64[(size_t)n * 64 + l] : IP[(size_t)n * 64 + l];
  const bool valid = ip >= 0;
  const int gi = ks0 + (valid ? ip : 0);
  __syncthreads();
  // scores: dot over hd*3 = 48 contiguous floats at offset h*48
  const float* kr = K + (size_t)gi * 384 + h * 48;
  float s = 0.f;
#pragma unroll
  for (int j = 0; j < 12; ++j) {
    float4 kv = ((const float4*)kr)[j];
    s = fmaf(kv.x, qs[h * 48 + j * 4 + 0], s);
    s = fmaf(kv.y, qs[h * 48 + j * 4 + 1], s);
    s = fmaf(kv.z, qs[h * 48 + j * 4 + 2], s);
    s = fmaf(kv.w, qs[h * 48 + j * 4 + 3], s);
  }
  s *= 0.25f;  // 1/sqrt(hd)
  if (!valid) s = -1e9f;
  float m = s;
  for (int off = 32; off; off >>= 1) m = fmaxf(m, __shfl_xor(m, off));
  float e = __expf(s - m);
  float sum = e;
  for (int off = 32; off; off >>= 1) sum += __shfl_xor(sum, off);
  attn_s[h][l] = e / sum;
  gi_s[h][l] = gi;
  __syncthreads();
  if (l < 48) {
    float acc = 0.f;
#pragma unroll 4
    for (int ll = 0; ll < 64; ++ll)
      acc = fmaf(attn_s[h][ll], V[(size_t)gi_s[h][ll] * 384 + h * 48 + l], acc);
    O[(size_t)n * 384 + h * 48 + l] = acc;
  }
}

// ---------------------------------------------------------------------------
// VN LayerNorm 1: h1 = VNLN(x + tgt2). Writes fp32 [(n*3+c)][128] AND
// bf16 hi/lo planes (split-GEMM A-operand).
// ---------------------------------------------------------------------------
__global__ __launch_bounds__(128) void ln1_kernel(
    const float* __restrict__ X, const float* __restrict__ T2,
    const float* __restrict__ G, const float* __restrict__ Bb,
    float* __restrict__ Hf, u16* __restrict__ Hhi, u16* __restrict__ Hlo)
{
  const int n = blockIdx.x, i = threadIdx.x;
  const size_t b0 = (size_t)n * 384 + i * 3;
  float v0 = X[b0 + 0] + T2[b0 + 0];
  float v1 = X[b0 + 1] + T2[b0 + 1];
  float v2 = X[b0 + 2] + T2[b0 + 2];
  float nn = sqrtf(v0 * v0 + v1 * v1 + v2 * v2 + 1e-6f);
  float s1 = nn, s2 = nn * nn;
  for (int off = 32; off; off >>= 1) { s1 += __shfl_xor(s1, off); s2 += __shfl_xor(s2, off); }
  __shared__ float red[4];
  if ((i & 63) == 0) { red[(i >> 6) * 2] = s1; red[(i >> 6) * 2 + 1] = s2; }
  __syncthreads();
  float mu = (red[0] + red[2]) * (1.0f / 128.0f);
  float ms = (red[1] + red[3]) * (1.0f / 128.0f);
  float var = ms - mu * mu;
  float nnew = (nn - mu) * rsqrtf(var + 1e-5f) * G[i] + Bb[i];
  float sc = nnew / nn;
  const size_t h0 = (size_t)n * 384 + i;  // [(n*3+c)][128]: n*384 + c*128 + i
  float o0 = v0 * sc, o1 = v1 * sc, o2 = v2 * sc;
  Hf[h0 + 0]   = o0;
  Hf[h0 + 128] = o1;
  Hf[h0 + 256] = o2;
  u16 q0 = f2b(o0), q1 = f2b(o1), q2 = f2b(o2);
  Hhi[h0 + 0] = q0;   Hlo[h0 + 0]   = f2b(o0 - b2f(q0));
  Hhi[h0 + 128] = q1; Hlo[h0 + 128] = f2b(o1 - b2f(q1));
  Hhi[h0 + 256] = q2; Hlo[h0 + 256] = f2b(o2 - b2f(q2));
}

// ---------------------------------------------------------------------------
// VN LayerNorm 2: out = VNLN(h1 + sum_z Gpart); fp32 in, fp32 out [n][i*3+c]
// ---------------------------------------------------------------------------
__global__ __launch_bounds__(128) void ln2_kernel(
    const float* __restrict__ Hf, const float* __restrict__ Gp,
    const float* __restrict__ G, const float* __restrict__ Bb, float* __restrict__ O)
{
  const int n = blockIdx.x, i = threadIdx.x;
  float v[3];
#pragma unroll
  for (int c = 0; c < 3; ++c) {
    float s = Hf[(size_t)n * 384 + c * 128 + i];
    const float* gp = Gp + (size_t)(n * 3 + c) * 128 + i;
#pragma unroll
    for (int z = 0; z < SPLITS; ++z) s += gp[(size_t)z * 6144 * 128];
    v[c] = s;
  }
  float nn = sqrtf(v[0] * v[0] + v[1] * v[1] + v[2] * v[2] + 1e-6f);
  float s1 = nn, s2 = nn * nn;
  for (int off = 32; off; off >>= 1) { s1 += __shfl_xor(s1, off); s2 += __shfl_xor(s2, off); }
  __shared__ float red[4];
  if ((i & 63) == 0) { red[(i >> 6) * 2] = s1; red[(i >> 6) * 2 + 1] = s2; }
  __syncthreads();
  float mu = (red[0] + red[2]) * (1.0f / 128.0f);
  float ms = (red[1] + red[3]) * (1.0f / 128.0f);
  float var = ms - mu * mu;
  float nnew = (nn - mu) * rsqrtf(var + 1e-5f) * G[i] + Bb[i];
  float sc = nnew / nn;
  const size_t o0 = (size_t)n * 384 + i * 3;
  O[o0 + 0] = v[0] * sc;
  O[o0 + 1] = v[1] * sc;
  O[o0 + 2] = v[2] * sc;
}

// ---------------------------------------------------------------------------
// VN-ReLU in place on F hi/lo planes; D given as fp16 bits.
// Layout: [(n*3+c)][o], stride DFF per c. f reconstructed hi+lo (~2^-17 rel).
// ---------------------------------------------------------------------------
__global__ __launch_bounds__(256) void vnrelu_kernel(
    u16* __restrict__ FH, u16* __restrict__ FL, const u16* __restrict__ D)
{
  const size_t idx = (size_t)blockIdx.x * 256 + threadIdx.x;  // n*DFF + o
  const size_t n = idx >> 11, o = idx & 2047;
  const size_t base = n * 3 * DFF + o;
  float f0 = b2f(FH[base])           + b2f(FL[base]);
  float f1 = b2f(FH[base + DFF])     + b2f(FL[base + DFF]);
  float f2 = b2f(FH[base + 2 * DFF]) + b2f(FL[base + 2 * DFF]);
  float d0 = h2f(D[base]), d1 = h2f(D[base + DFF]), d2 = h2f(D[base + 2 * DFF]);
  float dot = f0 * d0 + f1 * d1 + f2 * d2;
  if (dot < 0.0f) {
    float r = dot / (d0 * d0 + d1 * d1 + d2 * d2 + 1e-6f);
    float g0 = f0 - r * d0, g1 = f1 - r * d1, g2 = f2 - r * d2;
    u16 h0 = f2b(g0), h1 = f2b(g1), h2 = f2b(g2);
    FH[base] = h0;           FL[base] = f2b(g0 - b2f(h0));
    FH[base + DFF] = h1;     FL[base + DFF] = f2b(g1 - b2f(h1));
    FH[base + 2 * DFF] = h2; FL[base + 2 * DFF] = f2b(g2 - b2f(h2));
  }
}

// ---------------------------------------------------------------------------
// fp16 NT GEMM: C[M,N] = A[M,K]*B[N,K]^T, fp16 bits in, fp16 bits out.
// 128x128 tile, BK=32, 4 waves. LDS in fragment order [op][frag][lane][8]
// so ds_read/write_b128 are contiguous per wave (conflict-free).
// ---------------------------------------------------------------------------
__global__ __launch_bounds__(256) void gemm_f16(
    const u16* __restrict__ A, const u16* __restrict__ B,
    u16* __restrict__ C, int M, int N, int K)
{
  __shared__ __align__(16) u16 lds[2][8][64][8];  // 16 KiB
  const int tid = threadIdx.x;
  const int wave = tid >> 6, lane = tid & 63;
  const int bm = blockIdx.x, bn = blockIdx.y;
  const int nt = K >> 5;
  const int fr = lane & 15;
  const int kg = (lane >> 4) << 3;
  f32x4 acc[4][4] = {};
  const int wr = wave >> 1, wc = wave & 1;

  s16x8 ra[2], rb[2];
  auto load_regs = [&](int kt) {
    const int kk = (kt << 5) + kg;
#pragma unroll
    for (int i = 0; i < 2; ++i) {
      const int f = i * 4 + wave;
      ra[i] = *(const s16x8*)(A + (size_t)(bm * 128 + f * 16 + fr) * K + kk);
      rb[i] = *(const s16x8*)(B + (size_t)(bn * 128 + f * 16 + fr) * K + kk);
    }
  };
  auto write_lds = [&]() {
#pragma unroll
    for (int i = 0; i < 2; ++i) {
      const int f = i * 4 + wave;
      *(s16x8*)(&lds[0][f][lane][0]) = ra[i];
      *(s16x8*)(&lds[1][f][lane][0]) = rb[i];
    }
  };
  auto compute = [&]() {
    s16x8 af[4], bf[4];
#pragma unroll
    for (int m = 0; m < 4; ++m) af[m] = *(const s16x8*)(&lds[0][wr * 4 + m][lane][0]);
#pragma unroll
    for (int n2 = 0; n2 < 4; ++n2) bf[n2] = *(const s16x8*)(&lds[1][wc * 4 + n2][lane][0]);
#pragma unroll
    for (int m = 0; m < 4; ++m)
#pragma unroll
      for (int n2 = 0; n2 < 4; ++n2) mfma16h(acc[m][n2], af[m], bf[n2]);
  };

  load_regs(0);
  write_lds();
  for (int t = 0; t < nt; ++t) {
    __syncthreads();
    if (t + 1 < nt) load_regs(t + 1);
    compute();
    __syncthreads();
    if (t + 1 < nt) write_lds();
  }
  const int r0 = bm * 128 + wr * 64 + (lane >> 4) * 4;
  const int c0 = bn * 128 + wc * 64 + (lane & 15);
#pragma unroll
  for (int m = 0; m < 4; ++m)
#pragma unroll
    for (int n2 = 0; n2 < 4; ++n2)
#pragma unroll
      for (int r = 0; r < 4; ++r)
        C[(size_t)(r0 + m * 16 + r) * N + (c0 + n2 * 16)] = f2h(acc[m][n2][r]);
}

// ---------------------------------------------------------------------------
// Split-precision bf16 NT GEMM: acc += AhBh + AhBl + AlBh (~2^-17 relative).
// OUT=0: write bf16 hi/lo planes + fp16 plane (C1=hi, C2=lo, C3=fp16).
// OUT=1: fp32 partials at (float*)C1 + bz*M*N (split-K over gridDim.z).
// ---------------------------------------------------------------------------
template <int OUT>
__global__ __launch_bounds__(256) void gemm_split(
    const u16* __restrict__ AH, const u16* __restrict__ AL,
    const u16* __restrict__ BH, const u16* __restrict__ BL,
    void* __restrict__ C1, void* __restrict__ C2, void* __restrict__ C3,
    int M, int N, int K)
{
  __shared__ __align__(16) u16 lds[4][8][64][8];  // 32 KiB: AH,AL,BH,BL
  const int tid = threadIdx.x;
  const int wave = tid >> 6, lane = tid & 63;
  const int bm = blockIdx.x, bn = blockIdx.y, bz = blockIdx.z;
  const int kChunk = K / (int)gridDim.z;
  const int k0 = bz * kChunk;
  const int nt = kChunk >> 5;
  const int fr = lane & 15;
  const int kg = (lane >> 4) << 3;
  f32x4 acc[4][4] = {};
  const int wr = wave >> 1, wc = wave & 1;

  s16x8 rah[2], ral[2], rbh[2], rbl[2];
  auto load_regs = [&](int kt) {
    const int kk = k0 + (kt << 5) + kg;
#pragma unroll
    for (int i = 0; i < 2; ++i) {
      const int f = i * 4 + wave;
      const size_t ao = (size_t)(bm * 128 + f * 16 + fr) * K + kk;
      const size_t bo = (size_t)(bn * 128 + f * 16 + fr) * K + kk;
      rah[i] = *(const s16x8*)(AH + ao);
      ral[i] = *(const s16x8*)(AL + ao);
      rbh[i] = *(const s16x8*)(BH + bo);
      rbl[i] = *(const s16x8*)(BL + bo);
    }
  };
  auto write_lds = [&]() {
#pragma unroll
    for (int i = 0; i < 2; ++i) {
      const int f = i * 4 + wave;
      *(s16x8*)(&lds[0][f][lane][0]) = rah[i];
      *(s16x8*)(&lds[1][f][lane][0]) = ral[i];
      *(s16x8*)(&lds[2][f][lane][0]) = rbh[i];
      *(s16x8*)(&lds[3][f][lane][0]) = rbl[i];
    }
  };
  auto compute = [&]() {
    s16x8 ah[4], al[4], bh[4], bl[4];
#pragma unroll
    for (int m = 0; m < 4; ++m) {
      ah[m] = *(const s16x8*)(&lds[0][wr * 4 + m][lane][0]);
      al[m] = *(const s16x8*)(&lds[1][wr * 4 + m][lane][0]);
    }
#pragma unroll
    for (int n2 = 0; n2 < 4; ++n2) {
      bh[n2] = *(const s16x8*)(&lds[2][wc * 4 + n2][lane][0]);
      bl[n2] = *(const s16x8*)(&lds[3][wc * 4 + n2][lane][0]);
    }
#pragma unroll
    for (int m = 0; m < 4; ++m)
#pragma unroll
      for (int n2 = 0; n2 < 4; ++n2) {
        mfma16(acc[m][n2], ah[m], bh[n2]);
        mfma16(acc[m][n2], ah[m], bl[n2]);
        mfma16(acc[m][n2], al[m], bh[n2]);
      }
  };

  load_regs(0);
  write_lds();
  for (int t = 0; t < nt; ++t) {
    __syncthreads();
    if (t + 1 < nt) load_regs(t + 1);
    compute();
    __syncthreads();
    if (t + 1 < nt) write_lds();
  }
  const int r0 = bm * 128 + wr * 64 + (lane >> 4) * 4;
  const int c0 = bn * 128 + wc * 64 + (lane & 15);
  if constexpr (OUT == 0) {
    u16* CH = (u16*)C1;
    u16* CL = (u16*)C2;
    u16* CF = (u16*)C3;
#pragma unroll
    for (int m = 0; m < 4; ++m)
#pragma unroll
      for (int n2 = 0; n2 < 4; ++n2)
#pragma unroll
        for (int r = 0; r < 4; ++r) {
          float v = acc[m][n2][r];
          size_t idx = (size_t)(r0 + m * 16 + r) * N + (c0 + n2 * 16);
          u16 h = f2b(v);
          CH[idx] = h;
          CL[idx] = f2b(v - b2f(h));
          CF[idx] = f2h(v);
        }
  } else {
    float* C = (float*)C1 + (size_t)bz * M * N;
#pragma unroll
    for (int m = 0; m < 4; ++m)
#pragma unroll
      for (int n2 = 0; n2 < 4; ++n2)
#pragma unroll
        for (int r = 0; r < 4; ++r)
          C[(size_t)(r0 + m * 16 + r) * N + (c0 + n2 * 16)] = acc[m][n2][r];
  }
}

// ---------------------------------------------------------------------------
extern "C" void kernel_launch(void* const* d_in, const int* in_sizes, int n_in,
                              void* d_out, int out_size, void* d_ws, size_t ws_size,
                              hipStream_t stream)
{
  const float* tgt  = (const float*)d_in[0];
  const float* mem  = (const float*)d_in[1];
  const float* Wq   = (const float*)d_in[2];
  const float* Wk   = (const float*)d_in[3];
  const float* Wv   = (const float*)d_in[4];
  const float* Wo   = (const float*)d_in[5];
  const float* ln1g = (const float*)d_in[6];
  const float* ln1b = (const float*)d_in[7];
  const float* ln2g = (const float*)d_in[8];
  const float* ln2b = (const float*)d_in[9];
  const float* W1   = (const float*)d_in[10];
  const float* Wd   = (const float*)d_in[11];
  const float* W2   = (const float*)d_in[12];
  const int* ipair  = (const int*)d_in[13];
  const int* kbc    = (const int*)d_in[15];
  const int* ipb    = (const int*)d_in[16];
  float* out = (float*)d_out;

  char* p = (char*)d_ws;
  auto alloc = [&](size_t bytes) {
    char* r = p;
    p += (bytes + 255) & ~(size_t)255;
    return (void*)r;
  };
  float* q    = (float*)alloc((size_t)NQ * 384 * 4);
  float* kbuf = (float*)alloc((size_t)NK * 384 * 4);
  float* vbuf = (float*)alloc((size_t)NK * 384 * 4);
  float* aout = (float*)alloc((size_t)NQ * 384 * 4);
  float* tgt2 = (float*)alloc((size_t)NQ * 384 * 4);
  float* h1f  = (float*)alloc((size_t)NQ * 384 * 4);   // [(n*3+c)][128] fp32
  u16* h1hi = (u16*)alloc((size_t)6144 * 128 * 2);
  u16* h1lo = (u16*)alloc((size_t)6144 * 128 * 2);
  u16* W1hi = (u16*)alloc((size_t)DFF * 128 * 2);
  u16* W1lo = (u16*)alloc((size_t)DFF * 128 * 2);
  u16* Wdh  = (u16*)alloc((size_t)DFF * DFF * 2);      // fp16 bits
  u16* W2hi = (u16*)alloc((size_t)128 * DFF * 2);
  u16* W2lo = (u16*)alloc((size_t)128 * DFF * 2);
  u16* Fhi  = (u16*)alloc((size_t)6144 * DFF * 2);     // [(n*3+c)][dff] bf16 hi
  u16* Flo  = (u16*)alloc((size_t)6144 * DFF * 2);     // bf16 lo
  u16* Ff16 = (u16*)alloc((size_t)6144 * DFF * 2);     // fp16 plane (Wd A-op)
  u16* Dm   = (u16*)alloc((size_t)6144 * DFF * 2);     // fp16 bits
  float* Gp = (float*)Dm;  // alias: Dm (25 MB) dead before W2-gemm writes Gp (25 MB)
  int* dflag = (int*)alloc(256);

  detect_i64_kernel<<<1, 64, 0, stream>>>(ipair, dflag);
  quant_kernel<<<512, 256, 0, stream>>>(W1, W1hi, W1lo, DFF * 128);
  quantf16_kernel<<<2048, 256, 0, stream>>>(Wd, Wdh, DFF * DFF);
  quant_kernel<<<512, 256, 0, stream>>>(W2, W2hi, W2lo, 128 * DFF);

  proj_kernel<<<NQ / 2, 256, 0, stream>>>(tgt, Wq, q);
  proj_kernel<<<NK / 2, 256, 0, stream>>>(mem, Wk, kbuf);
  proj_kernel<<<NK / 2, 256, 0, stream>>>(mem, Wv, vbuf);
  attn_kernel<<<NQ, 512, 0, stream>>>(q, kbuf, vbuf, ipair, kbc, ipb, dflag, aout);
  proj_kernel<<<NQ / 2, 256, 0, stream>>>(aout, Wo, tgt2);
  ln1_kernel<<<NQ, 128, 0, stream>>>(tgt, tgt2, ln1g, ln1b, h1f, h1hi, h1lo);

  // F = h1 * W1^T  (M=6144, N=2048, K=128), split-bf16 -> hi/lo planes + fp16 plane
  gemm_split<0><<<dim3(48, 16, 1), 256, 0, stream>>>(h1hi, h1lo, W1hi, W1lo,
                                                     Fhi, Flo, Ff16, 6144, DFF, 128);
  // D = F * Wd^T   (M=6144, N=2048, K=2048), fp16 (2^-11 rel: LN2 amplification-safe)
  gemm_f16<<<dim3(48, 16, 1), 256, 0, stream>>>(Ff16, Wdh, Dm, 6144, DFF, DFF);
  vnrelu_kernel<<<(NQ * DFF) / 256, 256, 0, stream>>>(Fhi, Flo, Dm);
  // Gp partials = F' * W2^T  (M=6144, N=128, K=2048), split-bf16, split-K=8
  gemm_split<1><<<dim3(48, 1, SPLITS), 256, 0, stream>>>(Fhi, Flo, W2hi, W2lo,
                                                         Gp, nullptr, nullptr, 6144, 128, DFF);
  ln2_kernel<<<NQ, 128, 0, stream>>>(h1f, Gp, ln2g, ln2b, out);
}

// Round 5
// 329.707 us; speedup vs baseline: 1.0021x; 1.0021x over previous
//
#include <hip/hip_runtime.h>
#include <stdint.h>

// Problem constants (fixed by the reference)
#define NQ 2048
#define NK 4096
#define DFF 2048
#define SPLITS 8

using u16 = unsigned short;
typedef float f32x4 __attribute__((ext_vector_type(4)));
typedef short s16x8 __attribute__((ext_vector_type(8)));
typedef __attribute__((address_space(3))) void as3_void;
typedef __attribute__((address_space(1))) void as1_void;

__device__ __forceinline__ float b2f(u16 u) {
  return __uint_as_float(((uint32_t)u) << 16);
}
__device__ __forceinline__ u16 f2b(float f) {
  uint32_t u = __float_as_uint(f);
  uint32_t r = u + 0x7FFFu + ((u >> 16) & 1u);  // RNE
  return (u16)(r >> 16);
}
__device__ __forceinline__ u16 f2h(float f) {           // fp32 -> fp16 bits (RNE)
  _Float16 h = (_Float16)f;
  return __builtin_bit_cast(u16, h);
}
__device__ __forceinline__ float h2f(u16 u) {
  return (float)__builtin_bit_cast(_Float16, u);
}
__device__ __forceinline__ void mfma16(f32x4& d, s16x8 a, s16x8 b) {   // bf16
  asm volatile("v_mfma_f32_16x16x32_bf16 %0, %1, %2, %0" : "+v"(d) : "v"(a), "v"(b));
}
__device__ __forceinline__ void mfma16h(f32x4& d, s16x8 a, s16x8 b) {  // fp16
  asm volatile("v_mfma_f32_16x16x32_f16 %0, %1, %2, %0" : "+v"(d) : "v"(a), "v"(b));
}
// async global->LDS DMA, 16B/lane; LDS dest = wave-uniform base + lane*16.
// generic LDS ptr low 32 bits == LDS byte offset (gfx9 aperture encoding).
__device__ __forceinline__ void gll16(const void* g, const void* l) {
  uint32_t off = (uint32_t)(uintptr_t)l;
  off = (uint32_t)__builtin_amdgcn_readfirstlane((int)off);
  __builtin_amdgcn_global_load_lds((const as1_void*)(uintptr_t)g,
                                   (as3_void*)(uintptr_t)off, 16, 0, 0);
}

// ---------------------------------------------------------------------------
// int64-vs-int32 detector for index inputs (index values < 1024 -> int64 high
// words are all zero; genuine int32 random indices make that probability ~0).
// ---------------------------------------------------------------------------
__global__ void detect_i64_kernel(const int* __restrict__ IP, int* __restrict__ flag) {
  if (threadIdx.x == 0 && blockIdx.x == 0) {
    int f = 1;
    for (int j = 1; j < 128; j += 2) f &= (IP[j] == 0);
    *flag = f;
  }
}

// ---------------------------------------------------------------------------
// fp32 -> bf16 hi(/lo) plane quantizer. lo = bf16(v - hi) gives ~2^-17 rel pair.
// ---------------------------------------------------------------------------
__global__ __launch_bounds__(256) void quant_kernel(
    const float* __restrict__ S, u16* __restrict__ H, u16* __restrict__ L, int n)
{
  int i = blockIdx.x * 256 + threadIdx.x;
  const int stride = gridDim.x * 256;
  for (; i < n; i += stride) {
    float v = S[i];
    u16 h = f2b(v);
    H[i] = h;
    if (L) L[i] = f2b(v - b2f(h));
  }
}

// fp32 -> fp16 single-plane quantizer (for the Wd GEMM: 2^-11 rel)
__global__ __launch_bounds__(256) void quantf16_kernel(
    const float* __restrict__ S, u16* __restrict__ H, int n)
{
  int i = blockIdx.x * 256 + threadIdx.x;
  const int stride = gridDim.x * 256;
  for (; i < n; i += stride) H[i] = f2h(S[i]);
}

// ---------------------------------------------------------------------------
// Equivariant projection: Y[n,o,c] = sum_i W[o,i] * X[n,i,c]  (layout [n][i*3+c])
// fp32 throughout. 2 rows n per block.
// ---------------------------------------------------------------------------
__global__ __launch_bounds__(256) void proj_kernel(
    const float* __restrict__ X, const float* __restrict__ W, float* __restrict__ Y)
{
  __shared__ __align__(16) float xs[2][128][4];
  const int t = threadIdx.x;
  const int n0 = blockIdx.x * 2;
  for (int e = t; e < 768; e += 256) {
    int nl = (e >= 384);
    int r = e - nl * 384;
    xs[nl][r / 3][r % 3] = X[(size_t)(n0 + nl) * 384 + r];
  }
  __syncthreads();
  const int nl = t >> 7, o = t & 127;
  const float4* wrow = (const float4*)(W + o * 128);
  float a0 = 0.f, a1 = 0.f, a2 = 0.f;
#pragma unroll
  for (int j = 0; j < 32; ++j) {
    float4 wv = wrow[j];
    float w[4] = {wv.x, wv.y, wv.z, wv.w};
#pragma unroll
    for (int e = 0; e < 4; ++e) {
      float4 xv = *(const float4*)&xs[nl][j * 4 + e][0];
      a0 = fmaf(w[e], xv.x, a0);
      a1 = fmaf(w[e], xv.y, a1);
      a2 = fmaf(w[e], xv.z, a2);
    }
  }
  const size_t yb = (size_t)(n0 + nl) * 384 + o * 3;
  Y[yb + 0] = a0;
  Y[yb + 1] = a1;
  Y[yb + 2] = a2;
}

// ---------------------------------------------------------------------------
// Gathered multi-head attention, fp32. One block per query n; wave h = head,
// lane l = neighbor (L=64 == wave size).
// ---------------------------------------------------------------------------
__global__ __launch_bounds__(512) void attn_kernel(
    const float* __restrict__ Q, const float* __restrict__ K, const float* __restrict__ V,
    const int* __restrict__ IP, const int* __restrict__ KBC,
    const int* __restrict__ IPB, const int* __restrict__ FLAG, float* __restrict__ O)
{
  const int n = blockIdx.x;
  const int t = threadIdx.x;
  const int h = t >> 6, l = t & 63;
  __shared__ __align__(16) float qs[384];
  __shared__ float attn_s[8][64];
  __shared__ int gi_s[8][64];
  if (t < 96) ((float4*)qs)[t] = ((const float4*)(Q + (size_t)n * 384))[t];
  const int is64 = *FLAG;
  const long long* IP64 = (const long long*)IP;
  const long long* KBC64 = (const long long*)KBC;
  const long long* IPB64 = (const long long*)IPB;
  const int b = is64 ? (int)IPB64[n] : IPB[n];
  int ks0 = 0;
#pragma unroll
  for (int j = 0; j < 4; ++j) {
    int cnt = is64 ? (int)KBC64[j] : KBC[j];
    ks0 += (j < b) ? cnt : 0;  // exclusive cumsum
  }
  const int ip = is64 ? (int)IP64[(size_t)n * 64 + l] : IP[(size_t)n * 64 + l];
  const bool valid = ip >= 0;
  const int gi = ks0 + (valid ? ip : 0);
  __syncthreads();
  // scores: dot over hd*3 = 48 contiguous floats at offset h*48
  const float* kr = K + (size_t)gi * 384 + h * 48;
  float s = 0.f;
#pragma unroll
  for (int j = 0; j < 12; ++j) {
    float4 kv = ((const float4*)kr)[j];
    s = fmaf(kv.x, qs[h * 48 + j * 4 + 0], s);
    s = fmaf(kv.y, qs[h * 48 + j * 4 + 1], s);
    s = fmaf(kv.z, qs[h * 48 + j * 4 + 2], s);
    s = fmaf(kv.w, qs[h * 48 + j * 4 + 3], s);
  }
  s *= 0.25f;  // 1/sqrt(hd)
  if (!valid) s = -1e9f;
  float m = s;
  for (int off = 32; off; off >>= 1) m = fmaxf(m, __shfl_xor(m, off));
  float e = __expf(s - m);
  float sum = e;
  for (int off = 32; off; off >>= 1) sum += __shfl_xor(sum, off);
  attn_s[h][l] = e / sum;
  gi_s[h][l] = gi;
  __syncthreads();
  if (l < 48) {
    float acc = 0.f;
#pragma unroll 4
    for (int ll = 0; ll < 64; ++ll)
      acc = fmaf(attn_s[h][ll], V[(size_t)gi_s[h][ll] * 384 + h * 48 + l], acc);
    O[(size_t)n * 384 + h * 48 + l] = acc;
  }
}

// ---------------------------------------------------------------------------
// VN LayerNorm 1: h1 = VNLN(x + tgt2). Writes fp32 [(n*3+c)][128] AND
// bf16 hi/lo planes (split-GEMM A-operand).
// ---------------------------------------------------------------------------
__global__ __launch_bounds__(128) void ln1_kernel(
    const float* __restrict__ X, const float* __restrict__ T2,
    const float* __restrict__ G, const float* __restrict__ Bb,
    float* __restrict__ Hf, u16* __restrict__ Hhi, u16* __restrict__ Hlo)
{
  const int n = blockIdx.x, i = threadIdx.x;
  const size_t b0 = (size_t)n * 384 + i * 3;
  float v0 = X[b0 + 0] + T2[b0 + 0];
  float v1 = X[b0 + 1] + T2[b0 + 1];
  float v2 = X[b0 + 2] + T2[b0 + 2];
  float nn = sqrtf(v0 * v0 + v1 * v1 + v2 * v2 + 1e-6f);
  float s1 = nn, s2 = nn * nn;
  for (int off = 32; off; off >>= 1) { s1 += __shfl_xor(s1, off); s2 += __shfl_xor(s2, off); }
  __shared__ float red[4];
  if ((i & 63) == 0) { red[(i >> 6) * 2] = s1; red[(i >> 6) * 2 + 1] = s2; }
  __syncthreads();
  float mu = (red[0] + red[2]) * (1.0f / 128.0f);
  float ms = (red[1] + red[3]) * (1.0f / 128.0f);
  float var = ms - mu * mu;
  float nnew = (nn - mu) * rsqrtf(var + 1e-5f) * G[i] + Bb[i];
  float sc = nnew / nn;
  const size_t h0 = (size_t)n * 384 + i;  // [(n*3+c)][128]: n*384 + c*128 + i
  float o0 = v0 * sc, o1 = v1 * sc, o2 = v2 * sc;
  Hf[h0 + 0]   = o0;
  Hf[h0 + 128] = o1;
  Hf[h0 + 256] = o2;
  u16 q0 = f2b(o0), q1 = f2b(o1), q2 = f2b(o2);
  Hhi[h0 + 0] = q0;   Hlo[h0 + 0]   = f2b(o0 - b2f(q0));
  Hhi[h0 + 128] = q1; Hlo[h0 + 128] = f2b(o1 - b2f(q1));
  Hhi[h0 + 256] = q2; Hlo[h0 + 256] = f2b(o2 - b2f(q2));
}

// ---------------------------------------------------------------------------
// VN LayerNorm 2: out = VNLN(h1 + sum_z Gpart); fp32 in, fp32 out [n][i*3+c]
// ---------------------------------------------------------------------------
__global__ __launch_bounds__(128) void ln2_kernel(
    const float* __restrict__ Hf, const float* __restrict__ Gp,
    const float* __restrict__ G, const float* __restrict__ Bb, float* __restrict__ O)
{
  const int n = blockIdx.x, i = threadIdx.x;
  float v[3];
#pragma unroll
  for (int c = 0; c < 3; ++c) {
    float s = Hf[(size_t)n * 384 + c * 128 + i];
    const float* gp = Gp + (size_t)(n * 3 + c) * 128 + i;
#pragma unroll
    for (int z = 0; z < SPLITS; ++z) s += gp[(size_t)z * 6144 * 128];
    v[c] = s;
  }
  float nn = sqrtf(v[0] * v[0] + v[1] * v[1] + v[2] * v[2] + 1e-6f);
  float s1 = nn, s2 = nn * nn;
  for (int off = 32; off; off >>= 1) { s1 += __shfl_xor(s1, off); s2 += __shfl_xor(s2, off); }
  __shared__ float red[4];
  if ((i & 63) == 0) { red[(i >> 6) * 2] = s1; red[(i >> 6) * 2 + 1] = s2; }
  __syncthreads();
  float mu = (red[0] + red[2]) * (1.0f / 128.0f);
  float ms = (red[1] + red[3]) * (1.0f / 128.0f);
  float var = ms - mu * mu;
  float nnew = (nn - mu) * rsqrtf(var + 1e-5f) * G[i] + Bb[i];
  float sc = nnew / nn;
  const size_t o0 = (size_t)n * 384 + i * 3;
  O[o0 + 0] = v[0] * sc;
  O[o0 + 1] = v[1] * sc;
  O[o0 + 2] = v[2] * sc;
}

// ---------------------------------------------------------------------------
// VN-ReLU in place on F hi/lo planes; D given as fp16 bits.
// Layout: [(n*3+c)][o], stride DFF per c. f reconstructed hi+lo (~2^-17 rel).
// ---------------------------------------------------------------------------
__global__ __launch_bounds__(256) void vnrelu_kernel(
    u16* __restrict__ FH, u16* __restrict__ FL, const u16* __restrict__ D)
{
  const size_t idx = (size_t)blockIdx.x * 256 + threadIdx.x;  // n*DFF + o
  const size_t n = idx >> 11, o = idx & 2047;
  const size_t base = n * 3 * DFF + o;
  float f0 = b2f(FH[base])           + b2f(FL[base]);
  float f1 = b2f(FH[base + DFF])     + b2f(FL[base + DFF]);
  float f2 = b2f(FH[base + 2 * DFF]) + b2f(FL[base + 2 * DFF]);
  float d0 = h2f(D[base]), d1 = h2f(D[base + DFF]), d2 = h2f(D[base + 2 * DFF]);
  float dot = f0 * d0 + f1 * d1 + f2 * d2;
  if (dot < 0.0f) {
    float r = dot / (d0 * d0 + d1 * d1 + d2 * d2 + 1e-6f);
    float g0 = f0 - r * d0, g1 = f1 - r * d1, g2 = f2 - r * d2;
    u16 h0 = f2b(g0), h1 = f2b(g1), h2 = f2b(g2);
    FH[base] = h0;           FL[base] = f2b(g0 - b2f(h0));
    FH[base + DFF] = h1;     FL[base + DFF] = f2b(g1 - b2f(h1));
    FH[base + 2 * DFF] = h2; FL[base + 2 * DFF] = f2b(g2 - b2f(h2));
  }
}

// ---------------------------------------------------------------------------
// fp16 NT GEMM: C[M,N] = A[M,K]*B[N,K]^T, fp16 bits in, fp16 bits out.
// 128x128 tile, BK=32, 4 waves. m97 structure: double-buffered LDS filled by
// global_load_lds width=16 (DMA, no VGPR round-trip), ONE barrier per K-step.
// LDS in fragment order [buf][op][frag][lane][8]: DMA dest is linear
// (wave-uniform base + lane*16) and ds_read_b128 is contiguous per wave.
// ---------------------------------------------------------------------------
__global__ __launch_bounds__(256) void gemm_f16(
    const u16* __restrict__ A, const u16* __restrict__ B,
    u16* __restrict__ C, int M, int N, int K)
{
  __shared__ __align__(16) u16 lds[2][2][8][64][8];  // 32 KiB
  const int tid = threadIdx.x;
  const int wave = tid >> 6, lane = tid & 63;
  const int bm = blockIdx.x, bn = blockIdx.y;
  const int nt = K >> 5;
  const int fr = lane & 15;          // row within 16-row fragment
  const int kg = (lane >> 4) << 3;   // k sub-offset 0/8/16/24
  f32x4 acc[4][4] = {};
  const int wr = wave >> 1, wc = wave & 1;

  auto stage = [&](int buf, int kt) {
    const int kk = (kt << 5) + kg;
#pragma unroll
    for (int i = 0; i < 2; ++i) {
      const int f = i * 4 + wave;
      gll16(A + (size_t)(bm * 128 + f * 16 + fr) * K + kk, &lds[buf][0][f][0][0]);
      gll16(B + (size_t)(bn * 128 + f * 16 + fr) * K + kk, &lds[buf][1][f][0][0]);
    }
  };
  auto compute = [&](int buf) {
    s16x8 af[4], bf[4];
#pragma unroll
    for (int m = 0; m < 4; ++m) af[m] = *(const s16x8*)(&lds[buf][0][wr * 4 + m][lane][0]);
#pragma unroll
    for (int n2 = 0; n2 < 4; ++n2) bf[n2] = *(const s16x8*)(&lds[buf][1][wc * 4 + n2][lane][0]);
#pragma unroll
    for (int m = 0; m < 4; ++m)
#pragma unroll
      for (int n2 = 0; n2 < 4; ++n2) mfma16h(acc[m][n2], af[m], bf[n2]);
  };

  stage(0, 0);
  __syncthreads();
  int cur = 0;
  for (int t = 0; t + 1 < nt; ++t) {
    stage(cur ^ 1, t + 1);   // prefetch next K-tile via DMA
    compute(cur);
    __syncthreads();         // drains vmcnt(0): prefetch landed, reads of cur done
    cur ^= 1;
  }
  compute(cur);

  const int r0 = bm * 128 + wr * 64 + (lane >> 4) * 4;
  const int c0 = bn * 128 + wc * 64 + (lane & 15);
#pragma unroll
  for (int m = 0; m < 4; ++m)
#pragma unroll
    for (int n2 = 0; n2 < 4; ++n2)
#pragma unroll
      for (int r = 0; r < 4; ++r)
        C[(size_t)(r0 + m * 16 + r) * N + (c0 + n2 * 16)] = f2h(acc[m][n2][r]);
}

// ---------------------------------------------------------------------------
// Split-precision bf16 NT GEMM: acc += AhBh + AhBl + AlBh (~2^-17 relative).
// OUT=0: write bf16 hi/lo planes + fp16 plane (C1=hi, C2=lo, C3=fp16).
// OUT=1: fp32 partials at (float*)C1 + bz*M*N (split-K over gridDim.z).
// ---------------------------------------------------------------------------
template <int OUT>
__global__ __launch_bounds__(256) void gemm_split(
    const u16* __restrict__ AH, const u16* __restrict__ AL,
    const u16* __restrict__ BH, const u16* __restrict__ BL,
    void* __restrict__ C1, void* __restrict__ C2, void* __restrict__ C3,
    int M, int N, int K)
{
  __shared__ __align__(16) u16 lds[4][8][64][8];  // 32 KiB: AH,AL,BH,BL
  const int tid = threadIdx.x;
  const int wave = tid >> 6, lane = tid & 63;
  const int bm = blockIdx.x, bn = blockIdx.y, bz = blockIdx.z;
  const int kChunk = K / (int)gridDim.z;
  const int k0 = bz * kChunk;
  const int nt = kChunk >> 5;
  const int fr = lane & 15;
  const int kg = (lane >> 4) << 3;
  f32x4 acc[4][4] = {};
  const int wr = wave >> 1, wc = wave & 1;

  s16x8 rah[2], ral[2], rbh[2], rbl[2];
  auto load_regs = [&](int kt) {
    const int kk = k0 + (kt << 5) + kg;
#pragma unroll
    for (int i = 0; i < 2; ++i) {
      const int f = i * 4 + wave;
      const size_t ao = (size_t)(bm * 128 + f * 16 + fr) * K + kk;
      const size_t bo = (size_t)(bn * 128 + f * 16 + fr) * K + kk;
      rah[i] = *(const s16x8*)(AH + ao);
      ral[i] = *(const s16x8*)(AL + ao);
      rbh[i] = *(const s16x8*)(BH + bo);
      rbl[i] = *(const s16x8*)(BL + bo);
    }
  };
  auto write_lds = [&]() {
#pragma unroll
    for (int i = 0; i < 2; ++i) {
      const int f = i * 4 + wave;
      *(s16x8*)(&lds[0][f][lane][0]) = rah[i];
      *(s16x8*)(&lds[1][f][lane][0]) = ral[i];
      *(s16x8*)(&lds[2][f][lane][0]) = rbh[i];
      *(s16x8*)(&lds[3][f][lane][0]) = rbl[i];
    }
  };
  auto compute = [&]() {
    s16x8 ah[4], al[4], bh[4], bl[4];
#pragma unroll
    for (int m = 0; m < 4; ++m) {
      ah[m] = *(const s16x8*)(&lds[0][wr * 4 + m][lane][0]);
      al[m] = *(const s16x8*)(&lds[1][wr * 4 + m][lane][0]);
    }
#pragma unroll
    for (int n2 = 0; n2 < 4; ++n2) {
      bh[n2] = *(const s16x8*)(&lds[2][wc * 4 + n2][lane][0]);
      bl[n2] = *(const s16x8*)(&lds[3][wc * 4 + n2][lane][0]);
    }
#pragma unroll
    for (int m = 0; m < 4; ++m)
#pragma unroll
      for (int n2 = 0; n2 < 4; ++n2) {
        mfma16(acc[m][n2], ah[m], bh[n2]);
        mfma16(acc[m][n2], ah[m], bl[n2]);
        mfma16(acc[m][n2], al[m], bh[n2]);
      }
  };

  load_regs(0);
  write_lds();
  for (int t = 0; t < nt; ++t) {
    __syncthreads();
    if (t + 1 < nt) load_regs(t + 1);
    compute();
    __syncthreads();
    if (t + 1 < nt) write_lds();
  }
  const int r0 = bm * 128 + wr * 64 + (lane >> 4) * 4;
  const int c0 = bn * 128 + wc * 64 + (lane & 15);
  if constexpr (OUT == 0) {
    u16* CH = (u16*)C1;
    u16* CL = (u16*)C2;
    u16* CF = (u16*)C3;
#pragma unroll
    for (int m = 0; m < 4; ++m)
#pragma unroll
      for (int n2 = 0; n2 < 4; ++n2)
#pragma unroll
        for (int r = 0; r < 4; ++r) {
          float v = acc[m][n2][r];
          size_t idx = (size_t)(r0 + m * 16 + r) * N + (c0 + n2 * 16);
          u16 h = f2b(v);
          CH[idx] = h;
          CL[idx] = f2b(v - b2f(h));
          CF[idx] = f2h(v);
        }
  } else {
    float* C = (float*)C1 + (size_t)bz * M * N;
#pragma unroll
    for (int m = 0; m < 4; ++m)
#pragma unroll
      for (int n2 = 0; n2 < 4; ++n2)
#pragma unroll
        for (int r = 0; r < 4; ++r)
          C[(size_t)(r0 + m * 16 + r) * N + (c0 + n2 * 16)] = acc[m][n2][r];
  }
}

// ---------------------------------------------------------------------------
extern "C" void kernel_launch(void* const* d_in, const int* in_sizes, int n_in,
                              void* d_out, int out_size, void* d_ws, size_t ws_size,
                              hipStream_t stream)
{
  const float* tgt  = (const float*)d_in[0];
  const float* mem  = (const float*)d_in[1];
  const float* Wq   = (const float*)d_in[2];
  const float* Wk   = (const float*)d_in[3];
  const float* Wv   = (const float*)d_in[4];
  const float* Wo   = (const float*)d_in[5];
  const float* ln1g = (const float*)d_in[6];
  const float* ln1b = (const float*)d_in[7];
  const float* ln2g = (const float*)d_in[8];
  const float* ln2b = (const float*)d_in[9];
  const float* W1   = (const float*)d_in[10];
  const float* Wd   = (const float*)d_in[11];
  const float* W2   = (const float*)d_in[12];
  const int* ipair  = (const int*)d_in[13];
  const int* kbc    = (const int*)d_in[15];
  const int* ipb    = (const int*)d_in[16];
  float* out = (float*)d_out;

  char* p = (char*)d_ws;
  auto alloc = [&](size_t bytes) {
    char* r = p;
    p += (bytes + 255) & ~(size_t)255;
    return (void*)r;
  };
  float* q    = (float*)alloc((size_t)NQ * 384 * 4);
  float* kbuf = (float*)alloc((size_t)NK * 384 * 4);
  float* vbuf = (float*)alloc((size_t)NK * 384 * 4);
  float* aout = (float*)alloc((size_t)NQ * 384 * 4);
  float* tgt2 = (float*)alloc((size_t)NQ * 384 * 4);
  float* h1f  = (float*)alloc((size_t)NQ * 384 * 4);   // [(n*3+c)][128] fp32
  u16* h1hi = (u16*)alloc((size_t)6144 * 128 * 2);
  u16* h1lo = (u16*)alloc((size_t)6144 * 128 * 2);
  u16* W1hi = (u16*)alloc((size_t)DFF * 128 * 2);
  u16* W1lo = (u16*)alloc((size_t)DFF * 128 * 2);
  u16* Wdh  = (u16*)alloc((size_t)DFF * DFF * 2);      // fp16 bits
  u16* W2hi = (u16*)alloc((size_t)128 * DFF * 2);
  u16* W2lo = (u16*)alloc((size_t)128 * DFF * 2);
  u16* Fhi  = (u16*)alloc((size_t)6144 * DFF * 2);     // [(n*3+c)][dff] bf16 hi
  u16* Flo  = (u16*)alloc((size_t)6144 * DFF * 2);     // bf16 lo
  u16* Ff16 = (u16*)alloc((size_t)6144 * DFF * 2);     // fp16 plane (Wd A-op)
  u16* Dm   = (u16*)alloc((size_t)6144 * DFF * 2);     // fp16 bits
  float* Gp = (float*)Dm;  // alias: Dm (25 MB) dead before W2-gemm writes Gp (25 MB)
  int* dflag = (int*)alloc(256);

  detect_i64_kernel<<<1, 64, 0, stream>>>(ipair, dflag);
  quant_kernel<<<512, 256, 0, stream>>>(W1, W1hi, W1lo, DFF * 128);
  quantf16_kernel<<<2048, 256, 0, stream>>>(Wd, Wdh, DFF * DFF);
  quant_kernel<<<512, 256, 0, stream>>>(W2, W2hi, W2lo, 128 * DFF);

  proj_kernel<<<NQ / 2, 256, 0, stream>>>(tgt, Wq, q);
  proj_kernel<<<NK / 2, 256, 0, stream>>>(mem, Wk, kbuf);
  proj_kernel<<<NK / 2, 256, 0, stream>>>(mem, Wv, vbuf);
  attn_kernel<<<NQ, 512, 0, stream>>>(q, kbuf, vbuf, ipair, kbc, ipb, dflag, aout);
  proj_kernel<<<NQ / 2, 256, 0, stream>>>(aout, Wo, tgt2);
  ln1_kernel<<<NQ, 128, 0, stream>>>(tgt, tgt2, ln1g, ln1b, h1f, h1hi, h1lo);

  // F = h1 * W1^T  (M=6144, N=2048, K=128), split-bf16 -> hi/lo planes + fp16 plane
  gemm_split<0><<<dim3(48, 16, 1), 256, 0, stream>>>(h1hi, h1lo, W1hi, W1lo,
                                                     Fhi, Flo, Ff16, 6144, DFF, 128);
  // D = F * Wd^T   (M=6144, N=2048, K=2048), fp16 (2^-11 rel: LN2 amplification-safe)
  gemm_f16<<<dim3(48, 16, 1), 256, 0, stream>>>(Ff16, Wdh, Dm, 6144, DFF, DFF);
  vnrelu_kernel<<<(NQ * DFF) / 256, 256, 0, stream>>>(Fhi, Flo, Dm);
  // Gp partials = F' * W2^T  (M=6144, N=128, K=2048), split-bf16, split-K=8
  gemm_split<1><<<dim3(48, 1, SPLITS), 256, 0, stream>>>(Fhi, Flo, W2hi, W2lo,
                                                         Gp, nullptr, nullptr, 6144, 128, DFF);
  ln2_kernel<<<NQ, 128, 0, stream>>>(h1f, Gp, ln2g, ln2b, out);
}

// Round 6
// 328.984 us; speedup vs baseline: 1.0043x; 1.0022x over previous
//
#include <hip/hip_runtime.h>
#include <stdint.h>

// Problem constants (fixed by the reference)
#define NQ 2048
#define NK 4096
#define DFF 2048
#define SPLITS 8

using u16 = unsigned short;
typedef float f32x4 __attribute__((ext_vector_type(4)));
typedef short s16x8 __attribute__((ext_vector_type(8)));
typedef __attribute__((address_space(3))) void as3_void;
typedef __attribute__((address_space(1))) void as1_void;

__device__ __forceinline__ float b2f(u16 u) {
  return __uint_as_float(((uint32_t)u) << 16);
}
__device__ __forceinline__ u16 f2b(float f) {
  uint32_t u = __float_as_uint(f);
  uint32_t r = u + 0x7FFFu + ((u >> 16) & 1u);  // RNE
  return (u16)(r >> 16);
}
__device__ __forceinline__ u16 f2h(float f) {           // fp32 -> fp16 bits (RNE)
  _Float16 h = (_Float16)f;
  return __builtin_bit_cast(u16, h);
}
__device__ __forceinline__ float h2f(u16 u) {
  return (float)__builtin_bit_cast(_Float16, u);
}
__device__ __forceinline__ void mfma16(f32x4& d, s16x8 a, s16x8 b) {   // bf16
  asm volatile("v_mfma_f32_16x16x32_bf16 %0, %1, %2, %0" : "+v"(d) : "v"(a), "v"(b));
}
__device__ __forceinline__ void mfma16h(f32x4& d, s16x8 a, s16x8 b) {  // fp16
  asm volatile("v_mfma_f32_16x16x32_f16 %0, %1, %2, %0" : "+v"(d) : "v"(a), "v"(b));
}
// async global->LDS DMA, 16B/lane; LDS dest = wave-uniform base + lane*16.
__device__ __forceinline__ void gll16(const void* g, const void* l) {
  uint32_t off = (uint32_t)(uintptr_t)l;
  off = (uint32_t)__builtin_amdgcn_readfirstlane((int)off);
  __builtin_amdgcn_global_load_lds((const as1_void*)(uintptr_t)g,
                                   (as3_void*)(uintptr_t)off, 16, 0, 0);
}

// ---------------------------------------------------------------------------
// int64-vs-int32 detector for index inputs.
// ---------------------------------------------------------------------------
__global__ void detect_i64_kernel(const int* __restrict__ IP, int* __restrict__ flag) {
  if (threadIdx.x == 0 && blockIdx.x == 0) {
    int f = 1;
    for (int j = 1; j < 128; j += 2) f &= (IP[j] == 0);
    *flag = f;
  }
}

// ---------------------------------------------------------------------------
// fp32 -> bf16 hi(/lo) plane quantizer. lo = bf16(v - hi) gives ~2^-17 rel pair.
// ---------------------------------------------------------------------------
__global__ __launch_bounds__(256) void quant_kernel(
    const float* __restrict__ S, u16* __restrict__ H, u16* __restrict__ L, int n)
{
  int i = blockIdx.x * 256 + threadIdx.x;
  const int stride = gridDim.x * 256;
  for (; i < n; i += stride) {
    float v = S[i];
    u16 h = f2b(v);
    H[i] = h;
    if (L) L[i] = f2b(v - b2f(h));
  }
}

// fp32 -> fp16 single-plane quantizer (for the Wd GEMM: 2^-11 rel)
__global__ __launch_bounds__(256) void quantf16_kernel(
    const float* __restrict__ S, u16* __restrict__ H, int n)
{
  int i = blockIdx.x * 256 + threadIdx.x;
  const int stride = gridDim.x * 256;
  for (; i < n; i += stride) H[i] = f2h(S[i]);
}

// ---------------------------------------------------------------------------
// Equivariant projection: Y[n,o,c] = sum_i W[o,i] * X[n,i,c]  (layout [n][i*3+c])
// ---------------------------------------------------------------------------
__global__ __launch_bounds__(256) void proj_kernel(
    const float* __restrict__ X, const float* __restrict__ W, float* __restrict__ Y)
{
  __shared__ __align__(16) float xs[2][128][4];
  const int t = threadIdx.x;
  const int n0 = blockIdx.x * 2;
  for (int e = t; e < 768; e += 256) {
    int nl = (e >= 384);
    int r = e - nl * 384;
    xs[nl][r / 3][r % 3] = X[(size_t)(n0 + nl) * 384 + r];
  }
  __syncthreads();
  const int nl = t >> 7, o = t & 127;
  const float4* wrow = (const float4*)(W + o * 128);
  float a0 = 0.f, a1 = 0.f, a2 = 0.f;
#pragma unroll
  for (int j = 0; j < 32; ++j) {
    float4 wv = wrow[j];
    float w[4] = {wv.x, wv.y, wv.z, wv.w};
#pragma unroll
    for (int e = 0; e < 4; ++e) {
      float4 xv = *(const float4*)&xs[nl][j * 4 + e][0];
      a0 = fmaf(w[e], xv.x, a0);
      a1 = fmaf(w[e], xv.y, a1);
      a2 = fmaf(w[e], xv.z, a2);
    }
  }
  const size_t yb = (size_t)(n0 + nl) * 384 + o * 3;
  Y[yb + 0] = a0;
  Y[yb + 1] = a1;
  Y[yb + 2] = a2;
}

// ---------------------------------------------------------------------------
// Gathered multi-head attention, fp32.
// ---------------------------------------------------------------------------
__global__ __launch_bounds__(512) void attn_kernel(
    const float* __restrict__ Q, const float* __restrict__ K, const float* __restrict__ V,
    const int* __restrict__ IP, const int* __restrict__ KBC,
    const int* __restrict__ IPB, const int* __restrict__ FLAG, float* __restrict__ O)
{
  const int n = blockIdx.x;
  const int t = threadIdx.x;
  const int h = t >> 6, l = t & 63;
  __shared__ __align__(16) float qs[384];
  __shared__ float attn_s[8][64];
  __shared__ int gi_s[8][64];
  if (t < 96) ((float4*)qs)[t] = ((const float4*)(Q + (size_t)n * 384))[t];
  const int is64 = *FLAG;
  const long long* IP64 = (const long long*)IP;
  const long long* KBC64 = (const long long*)KBC;
  const long long* IPB64 = (const long long*)IPB;
  const int b = is64 ? (int)IPB64[n] : IPB[n];
  int ks0 = 0;
#pragma unroll
  for (int j = 0; j < 4; ++j) {
    int cnt = is64 ? (int)KBC64[j] : KBC[j];
    ks0 += (j < b) ? cnt : 0;  // exclusive cumsum
  }
  const int ip = is64 ? (int)IP64[(size_t)n * 64 + l] : IP[(size_t)n * 64 + l];
  const bool valid = ip >= 0;
  const int gi = ks0 + (valid ? ip : 0);
  __syncthreads();
  const float* kr = K + (size_t)gi * 384 + h * 48;
  float s = 0.f;
#pragma unroll
  for (int j = 0; j < 12; ++j) {
    float4 kv = ((const float4*)kr)[j];
    s = fmaf(kv.x, qs[h * 48 + j * 4 + 0], s);
    s = fmaf(kv.y, qs[h * 48 + j * 4 + 1], s);
    s = fmaf(kv.z, qs[h * 48 + j * 4 + 2], s);
    s = fmaf(kv.w, qs[h * 48 + j * 4 + 3], s);
  }
  s *= 0.25f;  // 1/sqrt(hd)
  if (!valid) s = -1e9f;
  float m = s;
  for (int off = 32; off; off >>= 1) m = fmaxf(m, __shfl_xor(m, off));
  float e = __expf(s - m);
  float sum = e;
  for (int off = 32; off; off >>= 1) sum += __shfl_xor(sum, off);
  attn_s[h][l] = e / sum;
  gi_s[h][l] = gi;
  __syncthreads();
  if (l < 48) {
    float acc = 0.f;
#pragma unroll 4
    for (int ll = 0; ll < 64; ++ll)
      acc = fmaf(attn_s[h][ll], V[(size_t)gi_s[h][ll] * 384 + h * 48 + l], acc);
    O[(size_t)n * 384 + h * 48 + l] = acc;
  }
}

// ---------------------------------------------------------------------------
// VN LayerNorm 1: h1 = VNLN(x + tgt2). Writes fp32 [(n*3+c)][128] AND
// bf16 hi/lo planes (split-GEMM A-operand).
// ---------------------------------------------------------------------------
__global__ __launch_bounds__(128) void ln1_kernel(
    const float* __restrict__ X, const float* __restrict__ T2,
    const float* __restrict__ G, const float* __restrict__ Bb,
    float* __restrict__ Hf, u16* __restrict__ Hhi, u16* __restrict__ Hlo)
{
  const int n = blockIdx.x, i = threadIdx.x;
  const size_t b0 = (size_t)n * 384 + i * 3;
  float v0 = X[b0 + 0] + T2[b0 + 0];
  float v1 = X[b0 + 1] + T2[b0 + 1];
  float v2 = X[b0 + 2] + T2[b0 + 2];
  float nn = sqrtf(v0 * v0 + v1 * v1 + v2 * v2 + 1e-6f);
  float s1 = nn, s2 = nn * nn;
  for (int off = 32; off; off >>= 1) { s1 += __shfl_xor(s1, off); s2 += __shfl_xor(s2, off); }
  __shared__ float red[4];
  if ((i & 63) == 0) { red[(i >> 6) * 2] = s1; red[(i >> 6) * 2 + 1] = s2; }
  __syncthreads();
  float mu = (red[0] + red[2]) * (1.0f / 128.0f);
  float ms = (red[1] + red[3]) * (1.0f / 128.0f);
  float var = ms - mu * mu;
  float nnew = (nn - mu) * rsqrtf(var + 1e-5f) * G[i] + Bb[i];
  float sc = nnew / nn;
  const size_t h0 = (size_t)n * 384 + i;
  float o0 = v0 * sc, o1 = v1 * sc, o2 = v2 * sc;
  Hf[h0 + 0]   = o0;
  Hf[h0 + 128] = o1;
  Hf[h0 + 256] = o2;
  u16 q0 = f2b(o0), q1 = f2b(o1), q2 = f2b(o2);
  Hhi[h0 + 0] = q0;   Hlo[h0 + 0]   = f2b(o0 - b2f(q0));
  Hhi[h0 + 128] = q1; Hlo[h0 + 128] = f2b(o1 - b2f(q1));
  Hhi[h0 + 256] = q2; Hlo[h0 + 256] = f2b(o2 - b2f(q2));
}

// ---------------------------------------------------------------------------
// VN LayerNorm 2: out = VNLN(h1 + sum_z Gpart); fp32 in, fp32 out [n][i*3+c]
// ---------------------------------------------------------------------------
__global__ __launch_bounds__(128) void ln2_kernel(
    const float* __restrict__ Hf, const float* __restrict__ Gp,
    const float* __restrict__ G, const float* __restrict__ Bb, float* __restrict__ O)
{
  const int n = blockIdx.x, i = threadIdx.x;
  float v[3];
#pragma unroll
  for (int c = 0; c < 3; ++c) {
    float s = Hf[(size_t)n * 384 + c * 128 + i];
    const float* gp = Gp + (size_t)(n * 3 + c) * 128 + i;
#pragma unroll
    for (int z = 0; z < SPLITS; ++z) s += gp[(size_t)z * 6144 * 128];
    v[c] = s;
  }
  float nn = sqrtf(v[0] * v[0] + v[1] * v[1] + v[2] * v[2] + 1e-6f);
  float s1 = nn, s2 = nn * nn;
  for (int off = 32; off; off >>= 1) { s1 += __shfl_xor(s1, off); s2 += __shfl_xor(s2, off); }
  __shared__ float red[4];
  if ((i & 63) == 0) { red[(i >> 6) * 2] = s1; red[(i >> 6) * 2 + 1] = s2; }
  __syncthreads();
  float mu = (red[0] + red[2]) * (1.0f / 128.0f);
  float ms = (red[1] + red[3]) * (1.0f / 128.0f);
  float var = ms - mu * mu;
  float nnew = (nn - mu) * rsqrtf(var + 1e-5f) * G[i] + Bb[i];
  float sc = nnew / nn;
  const size_t o0 = (size_t)n * 384 + i * 3;
  O[o0 + 0] = v[0] * sc;
  O[o0 + 1] = v[1] * sc;
  O[o0 + 2] = v[2] * sc;
}

// ---------------------------------------------------------------------------
// VN-ReLU in place on F hi/lo planes; D given as fp16 bits.
// ---------------------------------------------------------------------------
__global__ __launch_bounds__(256) void vnrelu_kernel(
    u16* __restrict__ FH, u16* __restrict__ FL, const u16* __restrict__ D)
{
  const size_t idx = (size_t)blockIdx.x * 256 + threadIdx.x;  // n*DFF + o
  const size_t n = idx >> 11, o = idx & 2047;
  const size_t base = n * 3 * DFF + o;
  float f0 = b2f(FH[base])           + b2f(FL[base]);
  float f1 = b2f(FH[base + DFF])     + b2f(FL[base + DFF]);
  float f2 = b2f(FH[base + 2 * DFF]) + b2f(FL[base + 2 * DFF]);
  float d0 = h2f(D[base]), d1 = h2f(D[base + DFF]), d2 = h2f(D[base + 2 * DFF]);
  float dot = f0 * d0 + f1 * d1 + f2 * d2;
  if (dot < 0.0f) {
    float r = dot / (d0 * d0 + d1 * d1 + d2 * d2 + 1e-6f);
    float g0 = f0 - r * d0, g1 = f1 - r * d1, g2 = f2 - r * d2;
    u16 h0 = f2b(g0), h1 = f2b(g1), h2 = f2b(g2);
    FH[base] = h0;           FL[base] = f2b(g0 - b2f(h0));
    FH[base + DFF] = h1;     FL[base + DFF] = f2b(g1 - b2f(h1));
    FH[base + 2 * DFF] = h2; FL[base + 2 * DFF] = f2b(g2 - b2f(h2));
  }
}

// ---------------------------------------------------------------------------
// fp16 NT GEMM, T3/T4 pipeline: 128x128 tile, BK=32, 4 waves.
// 3-buffer LDS ring, depth-2 global_load_lds prefetch, counted s_waitcnt
// vmcnt(4) + raw s_barrier (never drain to 0 in steady state).
// Invariants: at iter t entry, stages t and t+1 are in flight (4 gll each,
// per wave). vmcnt(4) retires stage t; barrier publishes it. Buffer being
// restaged, (t+2)%3 == (t-1)%3, was last read in compute(t-1), which every
// wave completed before this barrier.
// ---------------------------------------------------------------------------
__global__ __launch_bounds__(256) void gemm_f16(
    const u16* __restrict__ A, const u16* __restrict__ B,
    u16* __restrict__ C, int M, int N, int K)
{
  __shared__ __align__(16) u16 lds[3][2][8][64][8];  // 48 KiB, 3-deep ring
  const int tid = threadIdx.x;
  const int wave = tid >> 6, lane = tid & 63;
  const int bm = blockIdx.x, bn = blockIdx.y;
  const int nt = K >> 5;
  const int fr = lane & 15;          // row within 16-row fragment
  const int kg = (lane >> 4) << 3;   // k sub-offset 0/8/16/24
  f32x4 acc[4][4] = {};
  const int wr = wave >> 1, wc = wave & 1;

  auto stage = [&](int buf, int kt) {
    const int kk = (kt << 5) + kg;
#pragma unroll
    for (int i = 0; i < 2; ++i) {
      const int f = i * 4 + wave;
      gll16(A + (size_t)(bm * 128 + f * 16 + fr) * K + kk, &lds[buf][0][f][0][0]);
      gll16(B + (size_t)(bn * 128 + f * 16 + fr) * K + kk, &lds[buf][1][f][0][0]);
    }
  };
  auto compute = [&](int buf) {
    s16x8 af[4], bf[4];
#pragma unroll
    for (int m = 0; m < 4; ++m) af[m] = *(const s16x8*)(&lds[buf][0][wr * 4 + m][lane][0]);
#pragma unroll
    for (int n2 = 0; n2 < 4; ++n2) bf[n2] = *(const s16x8*)(&lds[buf][1][wc * 4 + n2][lane][0]);
#pragma unroll
    for (int m = 0; m < 4; ++m)
#pragma unroll
      for (int n2 = 0; n2 < 4; ++n2) mfma16h(acc[m][n2], af[m], bf[n2]);
  };

  stage(0, 0);
  if (nt > 1) stage(1, 1);
  for (int t = 0; t < nt; ++t) {
    if (t + 1 < nt) {
      asm volatile("s_waitcnt vmcnt(4)" ::: "memory");   // stage t landed (own lanes)
    } else {
      asm volatile("s_waitcnt vmcnt(0)" ::: "memory");   // final stage landed
    }
    __builtin_amdgcn_s_barrier();                        // whole buf t published
    __builtin_amdgcn_sched_barrier(0);
    if (t + 2 < nt) stage((t + 2) % 3, t + 2);           // issue-ahead, depth 2
    compute(t % 3);
  }

  const int r0 = bm * 128 + wr * 64 + (lane >> 4) * 4;
  const int c0 = bn * 128 + wc * 64 + (lane & 15);
#pragma unroll
  for (int m = 0; m < 4; ++m)
#pragma unroll
    for (int n2 = 0; n2 < 4; ++n2)
#pragma unroll
      for (int r = 0; r < 4; ++r)
        C[(size_t)(r0 + m * 16 + r) * N + (c0 + n2 * 16)] = f2h(acc[m][n2][r]);
}

// ---------------------------------------------------------------------------
// Split-precision bf16 NT GEMM: acc += AhBh + AhBl + AlBh (~2^-17 relative).
// OUT=0: write bf16 hi/lo planes + fp16 plane. OUT=1: fp32 split-K partials.
// ---------------------------------------------------------------------------
template <int OUT>
__global__ __launch_bounds__(256) void gemm_split(
    const u16* __restrict__ AH, const u16* __restrict__ AL,
    const u16* __restrict__ BH, const u16* __restrict__ BL,
    void* __restrict__ C1, void* __restrict__ C2, void* __restrict__ C3,
    int M, int N, int K)
{
  __shared__ __align__(16) u16 lds[4][8][64][8];  // 32 KiB: AH,AL,BH,BL
  const int tid = threadIdx.x;
  const int wave = tid >> 6, lane = tid & 63;
  const int bm = blockIdx.x, bn = blockIdx.y, bz = blockIdx.z;
  const int kChunk = K / (int)gridDim.z;
  const int k0 = bz * kChunk;
  const int nt = kChunk >> 5;
  const int fr = lane & 15;
  const int kg = (lane >> 4) << 3;
  f32x4 acc[4][4] = {};
  const int wr = wave >> 1, wc = wave & 1;

  s16x8 rah[2], ral[2], rbh[2], rbl[2];
  auto load_regs = [&](int kt) {
    const int kk = k0 + (kt << 5) + kg;
#pragma unroll
    for (int i = 0; i < 2; ++i) {
      const int f = i * 4 + wave;
      const size_t ao = (size_t)(bm * 128 + f * 16 + fr) * K + kk;
      const size_t bo = (size_t)(bn * 128 + f * 16 + fr) * K + kk;
      rah[i] = *(const s16x8*)(AH + ao);
      ral[i] = *(const s16x8*)(AL + ao);
      rbh[i] = *(const s16x8*)(BH + bo);
      rbl[i] = *(const s16x8*)(BL + bo);
    }
  };
  auto write_lds = [&]() {
#pragma unroll
    for (int i = 0; i < 2; ++i) {
      const int f = i * 4 + wave;
      *(s16x8*)(&lds[0][f][lane][0]) = rah[i];
      *(s16x8*)(&lds[1][f][lane][0]) = ral[i];
      *(s16x8*)(&lds[2][f][lane][0]) = rbh[i];
      *(s16x8*)(&lds[3][f][lane][0]) = rbl[i];
    }
  };
  auto compute = [&]() {
    s16x8 ah[4], al[4], bh[4], bl[4];
#pragma unroll
    for (int m = 0; m < 4; ++m) {
      ah[m] = *(const s16x8*)(&lds[0][wr * 4 + m][lane][0]);
      al[m] = *(const s16x8*)(&lds[1][wr * 4 + m][lane][0]);
    }
#pragma unroll
    for (int n2 = 0; n2 < 4; ++n2) {
      bh[n2] = *(const s16x8*)(&lds[2][wc * 4 + n2][lane][0]);
      bl[n2] = *(const s16x8*)(&lds[3][wc * 4 + n2][lane][0]);
    }
#pragma unroll
    for (int m = 0; m < 4; ++m)
#pragma unroll
      for (int n2 = 0; n2 < 4; ++n2) {
        mfma16(acc[m][n2], ah[m], bh[n2]);
        mfma16(acc[m][n2], ah[m], bl[n2]);
        mfma16(acc[m][n2], al[m], bh[n2]);
      }
  };

  load_regs(0);
  write_lds();
  for (int t = 0; t < nt; ++t) {
    __syncthreads();
    if (t + 1 < nt) load_regs(t + 1);
    compute();
    __syncthreads();
    if (t + 1 < nt) write_lds();
  }
  const int r0 = bm * 128 + wr * 64 + (lane >> 4) * 4;
  const int c0 = bn * 128 + wc * 64 + (lane & 15);
  if constexpr (OUT == 0) {
    u16* CH = (u16*)C1;
    u16* CL = (u16*)C2;
    u16* CF = (u16*)C3;
#pragma unroll
    for (int m = 0; m < 4; ++m)
#pragma unroll
      for (int n2 = 0; n2 < 4; ++n2)
#pragma unroll
        for (int r = 0; r < 4; ++r) {
          float v = acc[m][n2][r];
          size_t idx = (size_t)(r0 + m * 16 + r) * N + (c0 + n2 * 16);
          u16 h = f2b(v);
          CH[idx] = h;
          CL[idx] = f2b(v - b2f(h));
          CF[idx] = f2h(v);
        }
  } else {
    float* C = (float*)C1 + (size_t)bz * M * N;
#pragma unroll
    for (int m = 0; m < 4; ++m)
#pragma unroll
      for (int n2 = 0; n2 < 4; ++n2)
#pragma unroll
        for (int r = 0; r < 4; ++r)
          C[(size_t)(r0 + m * 16 + r) * N + (c0 + n2 * 16)] = acc[m][n2][r];
  }
}

// ---------------------------------------------------------------------------
extern "C" void kernel_launch(void* const* d_in, const int* in_sizes, int n_in,
                              void* d_out, int out_size, void* d_ws, size_t ws_size,
                              hipStream_t stream)
{
  const float* tgt  = (const float*)d_in[0];
  const float* mem  = (const float*)d_in[1];
  const float* Wq   = (const float*)d_in[2];
  const float* Wk   = (const float*)d_in[3];
  const float* Wv   = (const float*)d_in[4];
  const float* Wo   = (const float*)d_in[5];
  const float* ln1g = (const float*)d_in[6];
  const float* ln1b = (const float*)d_in[7];
  const float* ln2g = (const float*)d_in[8];
  const float* ln2b = (const float*)d_in[9];
  const float* W1   = (const float*)d_in[10];
  const float* Wd   = (const float*)d_in[11];
  const float* W2   = (const float*)d_in[12];
  const int* ipair  = (const int*)d_in[13];
  const int* kbc    = (const int*)d_in[15];
  const int* ipb    = (const int*)d_in[16];
  float* out = (float*)d_out;

  char* p = (char*)d_ws;
  auto alloc = [&](size_t bytes) {
    char* r = p;
    p += (bytes + 255) & ~(size_t)255;
    return (void*)r;
  };
  float* q    = (float*)alloc((size_t)NQ * 384 * 4);
  float* kbuf = (float*)alloc((size_t)NK * 384 * 4);
  float* vbuf = (float*)alloc((size_t)NK * 384 * 4);
  float* aout = (float*)alloc((size_t)NQ * 384 * 4);
  float* tgt2 = (float*)alloc((size_t)NQ * 384 * 4);
  float* h1f  = (float*)alloc((size_t)NQ * 384 * 4);   // [(n*3+c)][128] fp32
  u16* h1hi = (u16*)alloc((size_t)6144 * 128 * 2);
  u16* h1lo = (u16*)alloc((size_t)6144 * 128 * 2);
  u16* W1hi = (u16*)alloc((size_t)DFF * 128 * 2);
  u16* W1lo = (u16*)alloc((size_t)DFF * 128 * 2);
  u16* Wdh  = (u16*)alloc((size_t)DFF * DFF * 2);      // fp16 bits
  u16* W2hi = (u16*)alloc((size_t)128 * DFF * 2);
  u16* W2lo = (u16*)alloc((size_t)128 * DFF * 2);
  u16* Fhi  = (u16*)alloc((size_t)6144 * DFF * 2);     // [(n*3+c)][dff] bf16 hi
  u16* Flo  = (u16*)alloc((size_t)6144 * DFF * 2);     // bf16 lo
  u16* Ff16 = (u16*)alloc((size_t)6144 * DFF * 2);     // fp16 plane (Wd A-op)
  u16* Dm   = (u16*)alloc((size_t)6144 * DFF * 2);     // fp16 bits
  float* Gp = (float*)Dm;  // alias: Dm (25 MB) dead before W2-gemm writes Gp (25 MB)
  int* dflag = (int*)alloc(256);

  detect_i64_kernel<<<1, 64, 0, stream>>>(ipair, dflag);
  quant_kernel<<<512, 256, 0, stream>>>(W1, W1hi, W1lo, DFF * 128);
  quantf16_kernel<<<2048, 256, 0, stream>>>(Wd, Wdh, DFF * DFF);
  quant_kernel<<<512, 256, 0, stream>>>(W2, W2hi, W2lo, 128 * DFF);

  proj_kernel<<<NQ / 2, 256, 0, stream>>>(tgt, Wq, q);
  proj_kernel<<<NK / 2, 256, 0, stream>>>(mem, Wk, kbuf);
  proj_kernel<<<NK / 2, 256, 0, stream>>>(mem, Wv, vbuf);
  attn_kernel<<<NQ, 512, 0, stream>>>(q, kbuf, vbuf, ipair, kbc, ipb, dflag, aout);
  proj_kernel<<<NQ / 2, 256, 0, stream>>>(aout, Wo, tgt2);
  ln1_kernel<<<NQ, 128, 0, stream>>>(tgt, tgt2, ln1g, ln1b, h1f, h1hi, h1lo);

  // F = h1 * W1^T  (M=6144, N=2048, K=128), split-bf16 -> hi/lo planes + fp16 plane
  gemm_split<0><<<dim3(48, 16, 1), 256, 0, stream>>>(h1hi, h1lo, W1hi, W1lo,
                                                     Fhi, Flo, Ff16, 6144, DFF, 128);
  // D = F * Wd^T   (M=6144, N=2048, K=2048), fp16, T3/T4 counted-vmcnt pipeline
  gemm_f16<<<dim3(48, 16, 1), 256, 0, stream>>>(Ff16, Wdh, Dm, 6144, DFF, DFF);
  vnrelu_kernel<<<(NQ * DFF) / 256, 256, 0, stream>>>(Fhi, Flo, Dm);
  // Gp partials = F' * W2^T  (M=6144, N=128, K=2048), split-bf16, split-K=8
  gemm_split<1><<<dim3(48, 1, SPLITS), 256, 0, stream>>>(Fhi, Flo, W2hi, W2lo,
                                                         Gp, nullptr, nullptr, 6144, 128, DFF);
  ln2_kernel<<<NQ, 128, 0, stream>>>(h1f, Gp, ln2g, ln2b, out);
}